// Round 1
// baseline (686.618 us; speedup 1.0000x reference)
//
#include <hip/hip_runtime.h>
#include <math.h>

#define LN_EPS 1e-5f

constexpr int D = 1024;
constexpr int S = 4096;
constexpr int B = 4;
constexpr float NEG_TWO_PI = -6.283185307179586f;

// ---------------------------------------------------------------------------
// Kernel A: one block per row (b,s). Fused LayerNorm over D=1024, then a
// 1024-point radix-2 DIT FFT in LDS. Writes complex Y (split re/im planes,
// k contiguous) to workspace. All global access coalesced.
// ---------------------------------------------------------------------------
__global__ __launch_bounds__(256) void ln_fft_d(const float* __restrict__ x,
                                                const float* __restrict__ gamma,
                                                const float* __restrict__ beta,
                                                float* __restrict__ yre,
                                                float* __restrict__ yim) {
    __shared__ float re[D];
    __shared__ float im[D];
    __shared__ float red[24];

    const int row = blockIdx.x;          // b*S + s
    const int tid = threadIdx.x;
    const float* xr = x + (size_t)row * D;

    // ---- load 4 elements/thread, accumulate sum and sumsq ----
    float v[4];
    float sum = 0.f, sumsq = 0.f;
#pragma unroll
    for (int j = 0; j < 4; ++j) {
        float t = xr[tid + j * 256];
        v[j] = t;
        sum += t;
        sumsq += t * t;
    }
    // wave (64-lane) reduction
#pragma unroll
    for (int off = 32; off; off >>= 1) {
        sum   += __shfl_down(sum, off);
        sumsq += __shfl_down(sumsq, off);
    }
    const int wid = tid >> 6;
    if ((tid & 63) == 0) { red[wid] = sum; red[8 + wid] = sumsq; }
    __syncthreads();
    if (tid == 0) {
        float s0 = 0.f, s1 = 0.f;
        for (int w = 0; w < 4; ++w) { s0 += red[w]; s1 += red[8 + w]; }
        float mean = s0 * (1.0f / D);
        float var  = s1 * (1.0f / D) - mean * mean;
        red[16] = mean;
        red[17] = rsqrtf(var + LN_EPS);
    }
    __syncthreads();
    const float mean = red[16];
    const float rstd = red[17];

    // ---- normalize, scatter into LDS in bit-reversed order ----
#pragma unroll
    for (int j = 0; j < 4; ++j) {
        int i = tid + j * 256;
        float xn = (v[j] - mean) * rstd * gamma[i] + beta[i];
        int r = (int)(__brev((unsigned)i) >> 22);   // 10-bit reversal
        re[r] = xn;
        im[r] = 0.f;
    }
    __syncthreads();

    // ---- 10 radix-2 DIT stages ----
    for (int st = 1; st <= 10; ++st) {
        const int half = 1 << (st - 1);
        const float inv_len = 1.0f / (float)(1 << st);
        for (int t = tid; t < D / 2; t += 256) {
            int j = t & (half - 1);
            int idx = ((t >> (st - 1)) << st) + j;
            float sn, c;
            __sincosf(NEG_TWO_PI * (float)j * inv_len, &sn, &c);
            float ur = re[idx],        ui = im[idx];
            float vr = re[idx + half], vi = im[idx + half];
            float tr = vr * c - vi * sn;
            float ti = vr * sn + vi * c;
            re[idx]        = ur + tr;
            im[idx]        = ui + ti;
            re[idx + half] = ur - tr;
            im[idx + half] = ui - ti;
        }
        __syncthreads();
    }

    // ---- coalesced store of complex spectrum ----
#pragma unroll
    for (int j = 0; j < 4; ++j) {
        int k = tid + j * 256;
        size_t o = (size_t)row * D + k;
        yre[o] = re[k];
        yim[o] = im[k];
    }
}

// ---------------------------------------------------------------------------
// Kernel B: one block per (b,k) column. 4096-point radix-2 DIT FFT over the
// sequence dim in LDS (32 KB). Writes only the real part to d_out.
// Global access is strided (stride D floats) — relies on L2/L3 caching.
// ---------------------------------------------------------------------------
__global__ __launch_bounds__(256) void fft_s(const float* __restrict__ yre,
                                             const float* __restrict__ yim,
                                             float* __restrict__ out) {
    __shared__ float re[S];
    __shared__ float im[S];

    const int b = blockIdx.x >> 10;       // blockIdx.x / D
    const int k = blockIdx.x & (D - 1);   // blockIdx.x % D
    const int tid = threadIdx.x;
    const size_t base = (size_t)b * S * D + k;

    // ---- strided gather, bit-reversed into LDS ----
#pragma unroll
    for (int j = 0; j < 16; ++j) {
        int s = tid + j * 256;
        int r = (int)(__brev((unsigned)s) >> 20);   // 12-bit reversal
        size_t o = base + (size_t)s * D;
        re[r] = yre[o];
        im[r] = yim[o];
    }
    __syncthreads();

    // ---- 12 radix-2 DIT stages ----
    for (int st = 1; st <= 12; ++st) {
        const int half = 1 << (st - 1);
        const float inv_len = 1.0f / (float)(1 << st);
        for (int t = tid; t < S / 2; t += 256) {
            int j = t & (half - 1);
            int idx = ((t >> (st - 1)) << st) + j;
            float sn, c;
            __sincosf(NEG_TWO_PI * (float)j * inv_len, &sn, &c);
            float ur = re[idx],        ui = im[idx];
            float vr = re[idx + half], vi = im[idx + half];
            float tr = vr * c - vi * sn;
            float ti = vr * sn + vi * c;
            re[idx]        = ur + tr;
            im[idx]        = ui + ti;
            re[idx + half] = ur - tr;
            im[idx + half] = ui - ti;
        }
        __syncthreads();
    }

    // ---- strided scatter of the real part ----
#pragma unroll
    for (int j = 0; j < 16; ++j) {
        int t = tid + j * 256;
        out[base + (size_t)t * D] = re[t];
    }
}

extern "C" void kernel_launch(void* const* d_in, const int* in_sizes, int n_in,
                              void* d_out, int out_size, void* d_ws, size_t ws_size,
                              hipStream_t stream) {
    const float* x     = (const float*)d_in[0];
    const float* gamma = (const float*)d_in[1];
    const float* beta  = (const float*)d_in[2];
    float* out = (float*)d_out;

    // workspace layout: Y_re [B*S*D] | Y_im [B*S*D]  (128 MB total)
    float* yre = (float*)d_ws;
    float* yim = yre + (size_t)B * S * D;

    ln_fft_d<<<B * S, 256, 0, stream>>>(x, gamma, beta, yre, yim);
    fft_s<<<B * D, 256, 0, stream>>>(yre, yim, out);
}

// Round 2
// 265.397 us; speedup vs baseline: 2.5871x; 2.5871x over previous
//
#include <hip/hip_runtime.h>
#include <math.h>

#define LN_EPS 1e-5f

constexpr int D = 1024;
constexpr int S = 4096;
constexpr int B = 4;
constexpr float NEG_TWO_PI = -6.283185307179586f;

// XOR swizzle for 1024-entry float LDS arrays: kills the stride-512 / stride-32
// bank aliasing from bit-reversed scatters while keeping a bijection.
__device__ __forceinline__ int SW(int a) { return a ^ ((a >> 5) & 31); }

// ---------------------------------------------------------------------------
// Kernel A: one block per row (b,s). Fused LayerNorm over D=1024, then a
// 1024-point radix-2 DIT FFT in (swizzled) LDS. Writes interleaved complex
// float2 to workspace, coalesced.
// ---------------------------------------------------------------------------
__global__ __launch_bounds__(256) void ln_fft_d(const float* __restrict__ x,
                                                const float* __restrict__ gamma,
                                                const float* __restrict__ beta,
                                                float2* __restrict__ y) {
    __shared__ float re[D];
    __shared__ float im[D];
    __shared__ float red[20];

    const int row = blockIdx.x;          // b*S + s
    const int tid = threadIdx.x;
    const float4* xr4 = (const float4*)(x + (size_t)row * D);

    // ---- vectorized load (float4/thread), accumulate sum and sumsq ----
    float4 v4 = xr4[tid];
    float sum = v4.x + v4.y + v4.z + v4.w;
    float sumsq = v4.x * v4.x + v4.y * v4.y + v4.z * v4.z + v4.w * v4.w;
#pragma unroll
    for (int off = 32; off; off >>= 1) {
        sum   += __shfl_down(sum, off);
        sumsq += __shfl_down(sumsq, off);
    }
    const int wid = tid >> 6;
    if ((tid & 63) == 0) { red[wid] = sum; red[8 + wid] = sumsq; }
    __syncthreads();
    if (tid == 0) {
        float s0 = 0.f, s1 = 0.f;
        for (int w = 0; w < 4; ++w) { s0 += red[w]; s1 += red[8 + w]; }
        float mean = s0 * (1.0f / D);
        float var  = s1 * (1.0f / D) - mean * mean;
        red[16] = mean;
        red[17] = rsqrtf(var + LN_EPS);
    }
    __syncthreads();
    const float mean = red[16];
    const float rstd = red[17];

    // ---- normalize, scatter into LDS in bit-reversed (swizzled) order ----
    const float4 g4 = ((const float4*)gamma)[tid];
    const float4 b4 = ((const float4*)beta)[tid];
    const float vv[4] = {v4.x, v4.y, v4.z, v4.w};
    const float gg[4] = {g4.x, g4.y, g4.z, g4.w};
    const float bb[4] = {b4.x, b4.y, b4.z, b4.w};
#pragma unroll
    for (int j = 0; j < 4; ++j) {
        int i = 4 * tid + j;
        float xn = (vv[j] - mean) * rstd * gg[j] + bb[j];
        int r = (int)(__brev((unsigned)i) >> 22);   // 10-bit reversal
        int sidx = SW(r);
        re[sidx] = xn;
        im[sidx] = 0.f;
    }
    __syncthreads();

    // ---- 10 radix-2 DIT stages (swizzled LDS addressing) ----
    for (int st = 1; st <= 10; ++st) {
        const int half = 1 << (st - 1);
        const float inv_len = 1.0f / (float)(1 << st);
        for (int t = tid; t < D / 2; t += 256) {
            int j = t & (half - 1);
            int idx = ((t >> (st - 1)) << st) + j;
            int s1i = SW(idx), s2i = SW(idx + half);
            float sn, c;
            __sincosf(NEG_TWO_PI * (float)j * inv_len, &sn, &c);
            float ur = re[s1i], ui = im[s1i];
            float vr = re[s2i], vi = im[s2i];
            float tr = vr * c - vi * sn;
            float ti = vr * sn + vi * c;
            re[s1i] = ur + tr;
            im[s1i] = ui + ti;
            re[s2i] = ur - tr;
            im[s2i] = ui - ti;
        }
        __syncthreads();
    }

    // ---- coalesced interleaved store ----
    float2* yr = y + (size_t)row * D;
#pragma unroll
    for (int j = 0; j < 4; ++j) {
        int k = tid + j * 256;
        int sidx = SW(k);
        yr[k] = make_float2(re[sidx], im[sidx]);
    }
}

// ---------------------------------------------------------------------------
// Four-step FFT over S = 4096 = 64 x 64.
// Pass 1: for each (b, n1, d-tile): A[n1,k2] = FFT64 over n2 of Y[n1+64*n2],
//         then multiply by W_4096^{n1*k2}; store Z[b][k2][n1][d]  (in-place
//         over Y: each block writes exactly the rows/cols it read).
// Pass 2: for each (b, k2, d-tile): X[k2+64*k1] = FFT64 over n1 of Z; write
//         real part to out.
// All global access is 256-512B contiguous segments; LDS tile is [row][d]
// with lane = d, so every LDS op is conflict-free.
// ---------------------------------------------------------------------------
__global__ __launch_bounds__(256) void fft_s_p1(const float2* __restrict__ y,
                                                float2* __restrict__ z) {
    __shared__ float2 tile[64 * 64];     // 32 KB

    const int bid = blockIdx.x;
    const int dt = bid & 15;
    const int n1 = (bid >> 4) & 63;
    const int b  = bid >> 10;
    const int d0 = dt << 6;
    const int lane = threadIdx.x & 63;
    const int r4   = threadIdx.x >> 6;

    // gather 64 rows s = n1 + 64*n2, bit-reversed row placement
#pragma unroll
    for (int m = 0; m < 16; ++m) {
        int n2 = (m << 2) | r4;                      // wave-uniform
        int rr = (int)(__brev((unsigned)n2) >> 26);  // 6-bit reversal
        tile[(rr << 6) | lane] =
            y[(size_t)((b << 12) | (n2 << 6) | n1) * D + d0 + lane];
    }
    __syncthreads();

    // 6 radix-2 DIT stages over rows, batched across 64 d-columns
    for (int st = 1; st <= 6; ++st) {
        const int half = 1 << (st - 1);
        const float inv_len = 1.0f / (float)(1 << st);
#pragma unroll
        for (int it = 0; it < 8; ++it) {
            int t = threadIdx.x + (it << 8);
            int d = t & 63;
            int bf = t >> 6;
            int j = bf & (half - 1);
            int idx = ((bf >> (st - 1)) << st) | j;
            float sn, c;
            __sincosf(NEG_TWO_PI * (float)j * inv_len, &sn, &c);
            float2 u = tile[(idx << 6) | d];
            float2 w = tile[((idx + half) << 6) | d];
            float tr = w.x * c - w.y * sn;
            float ti = w.x * sn + w.y * c;
            tile[(idx << 6) | d] = make_float2(u.x + tr, u.y + ti);
            tile[((idx + half) << 6) | d] = make_float2(u.x - tr, u.y - ti);
        }
        __syncthreads();
    }

    // twiddle by W_4096^{n1*k2} and store Z[b][k2][n1][d]
    const float ang0 = NEG_TWO_PI * (float)n1 * (1.0f / 4096.0f);
#pragma unroll
    for (int m = 0; m < 16; ++m) {
        int k2 = (m << 2) | r4;                      // wave-uniform
        float2 vv = tile[(k2 << 6) | lane];
        float sn, c;
        __sincosf(ang0 * (float)k2, &sn, &c);
        float2 r = make_float2(vv.x * c - vv.y * sn, vv.x * sn + vv.y * c);
        z[(size_t)((b << 12) | (k2 << 6) | n1) * D + d0 + lane] = r;
    }
}

__global__ __launch_bounds__(256) void fft_s_p2(const float2* __restrict__ z,
                                                float* __restrict__ out) {
    __shared__ float2 tile[64 * 64];     // 32 KB

    const int bid = blockIdx.x;
    const int dt = bid & 15;
    const int k2 = (bid >> 4) & 63;
    const int b  = bid >> 10;
    const int d0 = dt << 6;
    const int lane = threadIdx.x & 63;
    const int r4   = threadIdx.x >> 6;

    // contiguous-segment gather over n1, bit-reversed row placement
#pragma unroll
    for (int m = 0; m < 16; ++m) {
        int n1 = (m << 2) | r4;
        int rr = (int)(__brev((unsigned)n1) >> 26);
        tile[(rr << 6) | lane] =
            z[(size_t)((b << 12) | (k2 << 6) | n1) * D + d0 + lane];
    }
    __syncthreads();

    for (int st = 1; st <= 6; ++st) {
        const int half = 1 << (st - 1);
        const float inv_len = 1.0f / (float)(1 << st);
#pragma unroll
        for (int it = 0; it < 8; ++it) {
            int t = threadIdx.x + (it << 8);
            int d = t & 63;
            int bf = t >> 6;
            int j = bf & (half - 1);
            int idx = ((bf >> (st - 1)) << st) | j;
            float sn, c;
            __sincosf(NEG_TWO_PI * (float)j * inv_len, &sn, &c);
            float2 u = tile[(idx << 6) | d];
            float2 w = tile[((idx + half) << 6) | d];
            float tr = w.x * c - w.y * sn;
            float ti = w.x * sn + w.y * c;
            tile[(idx << 6) | d] = make_float2(u.x + tr, u.y + ti);
            tile[((idx + half) << 6) | d] = make_float2(u.x - tr, u.y - ti);
        }
        __syncthreads();
    }

    // X[k2 + 64*k1] = row k1; write real part, 256B contiguous segments
#pragma unroll
    for (int m = 0; m < 16; ++m) {
        int k1 = (m << 2) | r4;                      // wave-uniform
        out[(size_t)((b << 12) | (k1 << 6) | k2) * D + d0 + lane] =
            tile[(k1 << 6) | lane].x;
    }
}

extern "C" void kernel_launch(void* const* d_in, const int* in_sizes, int n_in,
                              void* d_out, int out_size, void* d_ws, size_t ws_size,
                              hipStream_t stream) {
    const float* x     = (const float*)d_in[0];
    const float* gamma = (const float*)d_in[1];
    const float* beta  = (const float*)d_in[2];
    float* out = (float*)d_out;

    // workspace: interleaved complex Y [B*S*D] float2 = 128 MB; pass 1 of the
    // S-FFT runs in-place on it.
    float2* y = (float2*)d_ws;

    ln_fft_d<<<B * S, 256, 0, stream>>>(x, gamma, beta, y);
    fft_s_p1<<<B * 64 * 16, 256, 0, stream>>>(y, y);
    fft_s_p2<<<B * 64 * 16, 256, 0, stream>>>(y, out);
}

// Round 3
// 232.672 us; speedup vs baseline: 2.9510x; 1.1407x over previous
//
#include <hip/hip_runtime.h>
#include <math.h>

#define LN_EPS 1e-5f

constexpr int D = 1024;
constexpr int S = 4096;
constexpr int B = 4;
constexpr float NEG_TWO_PI = -6.283185307179586f;

__device__ __forceinline__ float2 cmul(float2 a, float2 b) {
    return make_float2(a.x * b.x - a.y * b.y, a.x * b.y + a.y * b.x);
}
__device__ __forceinline__ float2 csq(float2 a) {
    return make_float2(a.x * a.x - a.y * a.y, 2.f * a.x * a.y);
}

// Bank swizzle for the 1024-float re/im arrays. Radix-4 stage address sets
// vary in bits {2..7}, {0,1,4..7}, {0..3,6,7}; xor-folding bit5->00101,
// bit6->01010, bit7->10001 makes every access <=2-way (free on CDNA).
__device__ __forceinline__ int SWX(int a) {
    int r = a;
    r ^= (-((a >> 5) & 1)) & 5;
    r ^= (-((a >> 6) & 1)) & 10;
    r ^= (-((a >> 7) & 1)) & 17;
    return r;
}

// ---------------------------------------------------------------------------
// Kernel A: LayerNorm + 1024-pt radix-4 DIT FFT in LDS (twiddles from table).
// ---------------------------------------------------------------------------
__global__ __launch_bounds__(256) void ln_fft_d(const float* __restrict__ x,
                                                const float* __restrict__ gamma,
                                                const float* __restrict__ beta,
                                                float2* __restrict__ y) {
    __shared__ float re[D];
    __shared__ float im[D];
    __shared__ float2 twA[256];   // W_1024^t, t=0..255
    __shared__ float red[20];

    const int row = blockIdx.x;          // b*S + s
    const int tid = threadIdx.x;

    {   // twiddle table: one sincos per thread
        float sn, c;
        __sincosf(NEG_TWO_PI * (float)tid * (1.0f / 1024.0f), &sn, &c);
        twA[tid] = make_float2(c, sn);
    }

    // ---- vectorized load + LN statistics ----
    const float4 v4 = ((const float4*)(x + (size_t)row * D))[tid];
    float sum = v4.x + v4.y + v4.z + v4.w;
    float sumsq = v4.x * v4.x + v4.y * v4.y + v4.z * v4.z + v4.w * v4.w;
#pragma unroll
    for (int off = 32; off; off >>= 1) {
        sum   += __shfl_down(sum, off);
        sumsq += __shfl_down(sumsq, off);
    }
    const int wid = tid >> 6;
    if ((tid & 63) == 0) { red[wid] = sum; red[8 + wid] = sumsq; }
    __syncthreads();
    if (tid == 0) {
        float s0 = red[0] + red[1] + red[2] + red[3];
        float s1 = red[8] + red[9] + red[10] + red[11];
        float mean = s0 * (1.0f / D);
        float var  = s1 * (1.0f / D) - mean * mean;
        red[16] = mean;
        red[17] = rsqrtf(var + LN_EPS);
    }
    __syncthreads();
    const float mean = red[16];
    const float rstd = red[17];

    // ---- normalize, scatter in base-4 digit-reversed order ----
    const float4 g4 = ((const float4*)gamma)[tid];
    const float4 b4 = ((const float4*)beta)[tid];
    const float vv[4] = {v4.x, v4.y, v4.z, v4.w};
    const float gg[4] = {g4.x, g4.y, g4.z, g4.w};
    const float bb[4] = {b4.x, b4.y, b4.z, b4.w};
#pragma unroll
    for (int j = 0; j < 4; ++j) {
        int i = 4 * tid + j;
        float xn = (vv[j] - mean) * rstd * gg[j] + bb[j];
        unsigned br = __brev((unsigned)i) >> 22;                    // 10-bit reverse
        int dr = (int)(((br & 0x155u) << 1) | ((br & 0x2AAu) >> 1)); // swap bit pairs
        int p = SWX(dr);
        re[p] = xn;
        im[p] = 0.f;
    }
    __syncthreads();

    // ---- 5 radix-4 DIT stages, one butterfly per thread per stage ----
#pragma unroll
    for (int st = 0; st < 5; ++st) {
        const int lq = 2 * st;
        const int q = 1 << lq;
        const int j = tid & (q - 1);
        const int i0 = ((tid & ~(q - 1)) << 2) + j;
        const int p0 = SWX(i0);
        const int p1 = SWX(i0 + q);
        const int p2 = SWX(i0 + 2 * q);
        const int p3 = SWX(i0 + 3 * q);
        const float2 w1 = twA[j << (8 - lq)];
        const float2 w2 = csq(w1);
        const float2 w3 = cmul(w1, w2);
        float2 a0 = make_float2(re[p0], im[p0]);
        float2 a1 = cmul(make_float2(re[p1], im[p1]), w1);
        float2 a2 = cmul(make_float2(re[p2], im[p2]), w2);
        float2 a3 = cmul(make_float2(re[p3], im[p3]), w3);
        float t0r = a0.x + a2.x, t0i = a0.y + a2.y;
        float t1r = a0.x - a2.x, t1i = a0.y - a2.y;
        float t2r = a1.x + a3.x, t2i = a1.y + a3.y;
        float t3r = a1.y - a3.y, t3i = a3.x - a1.x;   // -i*(a1-a3)
        re[p0] = t0r + t2r; im[p0] = t0i + t2i;
        re[p1] = t1r + t3r; im[p1] = t1i + t3i;
        re[p2] = t0r - t2r; im[p2] = t0i - t2i;
        re[p3] = t1r - t3r; im[p3] = t1i - t3i;
        __syncthreads();
    }

    // ---- coalesced interleaved store ----
    float2* yr = y + (size_t)row * D;
#pragma unroll
    for (int jj = 0; jj < 4; ++jj) {
        int k = tid + jj * 256;
        int p = SWX(k);
        yr[k] = make_float2(re[p], im[p]);
    }
}

// ---------------------------------------------------------------------------
// Four-step FFT over S = 4096 = 64 x 64, radix-4 64-pt FFTs, twiddle table.
// Pass 1: fixed n1: FFT64 over n2, multiply by W_4096^{n1*k2}, store
//         Z[b][k2][n1][d] in place. Pass 2: fixed k2: FFT64 over n1, write
//         real part to out[b][k2+64*k1][d].
// ---------------------------------------------------------------------------
__global__ __launch_bounds__(256) void fft_s_p1(const float2* __restrict__ y,
                                                float2* __restrict__ z) {
    __shared__ float2 tile[64 * 64];     // 32 KB, [row][d], lane=d: conflict-free
    __shared__ float2 tw64[16];          // W_64^t

    const int bid = blockIdx.x;
    const int dt = bid & 15;
    const int n1 = (bid >> 4) & 63;
    const int b  = bid >> 10;
    const int d0 = dt << 6;
    const int lane = threadIdx.x & 63;
    const int r4   = threadIdx.x >> 6;

    if (threadIdx.x < 16) {
        float sn, c;
        __sincosf(NEG_TWO_PI * (float)threadIdx.x * (1.0f / 64.0f), &sn, &c);
        tw64[threadIdx.x] = make_float2(c, sn);
    }

    // gather rows s = n1 + 64*n2, base-4 digit-reversed row placement
#pragma unroll
    for (int m = 0; m < 16; ++m) {
        int n2 = (m << 2) | r4;                       // wave-uniform
        unsigned br = __brev((unsigned)n2) >> 26;     // 6-bit reverse
        int rr = (int)(((br & 0x15u) << 1) | ((br & 0x2Au) >> 1));
        tile[(rr << 6) | lane] =
            y[(size_t)((b << 12) | (n2 << 6) | n1) * D + d0 + lane];
    }
    __syncthreads();

    // 3 radix-4 DIT stages over rows, batched across 64 d-columns
#pragma unroll
    for (int st = 0; st < 3; ++st) {
        const int lq = 2 * st;
        const int q = 1 << lq;
#pragma unroll
        for (int it = 0; it < 4; ++it) {
            int t = threadIdx.x + (it << 8);
            int d = t & 63;
            int bf = t >> 6;
            int j = bf & (q - 1);
            int i0 = ((bf & ~(q - 1)) << 2) + j;
            float2 w1 = tw64[j << (4 - lq)];
            float2 w2 = csq(w1);
            float2 w3 = cmul(w1, w2);
            float2 a0 = tile[(i0 << 6) | d];
            float2 a1 = cmul(tile[((i0 + q) << 6) | d], w1);
            float2 a2 = cmul(tile[((i0 + 2 * q) << 6) | d], w2);
            float2 a3 = cmul(tile[((i0 + 3 * q) << 6) | d], w3);
            float t0r = a0.x + a2.x, t0i = a0.y + a2.y;
            float t1r = a0.x - a2.x, t1i = a0.y - a2.y;
            float t2r = a1.x + a3.x, t2i = a1.y + a3.y;
            float t3r = a1.y - a3.y, t3i = a3.x - a1.x;
            tile[(i0 << 6) | d]           = make_float2(t0r + t2r, t0i + t2i);
            tile[((i0 + q) << 6) | d]     = make_float2(t1r + t3r, t1i + t3i);
            tile[((i0 + 2 * q) << 6) | d] = make_float2(t0r - t2r, t0i - t2i);
            tile[((i0 + 3 * q) << 6) | d] = make_float2(t1r - t3r, t1i - t3i);
        }
        __syncthreads();
    }

    // twiddle by W_4096^{n1*k2}, store Z[b][k2][n1][d]
    const float ang0 = NEG_TWO_PI * (float)n1 * (1.0f / 4096.0f);
#pragma unroll
    for (int m = 0; m < 16; ++m) {
        int k2 = (m << 2) | r4;                       // wave-uniform
        float2 vv = tile[(k2 << 6) | lane];
        float sn, c;
        __sincosf(ang0 * (float)k2, &sn, &c);
        float2 r = make_float2(vv.x * c - vv.y * sn, vv.x * sn + vv.y * c);
        z[(size_t)((b << 12) | (k2 << 6) | n1) * D + d0 + lane] = r;
    }
}

__global__ __launch_bounds__(256) void fft_s_p2(const float2* __restrict__ z,
                                                float* __restrict__ out) {
    __shared__ float2 tile[64 * 64];
    __shared__ float2 tw64[16];

    const int bid = blockIdx.x;
    const int dt = bid & 15;
    const int k2 = (bid >> 4) & 63;
    const int b  = bid >> 10;
    const int d0 = dt << 6;
    const int lane = threadIdx.x & 63;
    const int r4   = threadIdx.x >> 6;

    if (threadIdx.x < 16) {
        float sn, c;
        __sincosf(NEG_TWO_PI * (float)threadIdx.x * (1.0f / 64.0f), &sn, &c);
        tw64[threadIdx.x] = make_float2(c, sn);
    }

#pragma unroll
    for (int m = 0; m < 16; ++m) {
        int n1 = (m << 2) | r4;
        unsigned br = __brev((unsigned)n1) >> 26;
        int rr = (int)(((br & 0x15u) << 1) | ((br & 0x2Au) >> 1));
        tile[(rr << 6) | lane] =
            z[(size_t)((b << 12) | (k2 << 6) | n1) * D + d0 + lane];
    }
    __syncthreads();

#pragma unroll
    for (int st = 0; st < 3; ++st) {
        const int lq = 2 * st;
        const int q = 1 << lq;
#pragma unroll
        for (int it = 0; it < 4; ++it) {
            int t = threadIdx.x + (it << 8);
            int d = t & 63;
            int bf = t >> 6;
            int j = bf & (q - 1);
            int i0 = ((bf & ~(q - 1)) << 2) + j;
            float2 w1 = tw64[j << (4 - lq)];
            float2 w2 = csq(w1);
            float2 w3 = cmul(w1, w2);
            float2 a0 = tile[(i0 << 6) | d];
            float2 a1 = cmul(tile[((i0 + q) << 6) | d], w1);
            float2 a2 = cmul(tile[((i0 + 2 * q) << 6) | d], w2);
            float2 a3 = cmul(tile[((i0 + 3 * q) << 6) | d], w3);
            float t0r = a0.x + a2.x, t0i = a0.y + a2.y;
            float t1r = a0.x - a2.x, t1i = a0.y - a2.y;
            float t2r = a1.x + a3.x, t2i = a1.y + a3.y;
            float t3r = a1.y - a3.y, t3i = a3.x - a1.x;
            tile[(i0 << 6) | d]           = make_float2(t0r + t2r, t0i + t2i);
            tile[((i0 + q) << 6) | d]     = make_float2(t1r + t3r, t1i + t3i);
            tile[((i0 + 2 * q) << 6) | d] = make_float2(t0r - t2r, t0i - t2i);
            tile[((i0 + 3 * q) << 6) | d] = make_float2(t1r - t3r, t1i - t3i);
        }
        __syncthreads();
    }

    // X[k2 + 64*k1] = row k1; write real part
#pragma unroll
    for (int m = 0; m < 16; ++m) {
        int k1 = (m << 2) | r4;
        out[(size_t)((b << 12) | (k1 << 6) | k2) * D + d0 + lane] =
            tile[(k1 << 6) | lane].x;
    }
}

extern "C" void kernel_launch(void* const* d_in, const int* in_sizes, int n_in,
                              void* d_out, int out_size, void* d_ws, size_t ws_size,
                              hipStream_t stream) {
    const float* x     = (const float*)d_in[0];
    const float* gamma = (const float*)d_in[1];
    const float* beta  = (const float*)d_in[2];
    float* out = (float*)d_out;

    float2* y = (float2*)d_ws;   // 128 MB interleaved complex; p1 runs in place

    ln_fft_d<<<B * S, 256, 0, stream>>>(x, gamma, beta, y);
    fft_s_p1<<<B * 64 * 16, 256, 0, stream>>>(y, y);
    fft_s_p2<<<B * 64 * 16, 256, 0, stream>>>(y, out);
}

// Round 4
// 178.437 us; speedup vs baseline: 3.8479x; 1.3039x over previous
//
#include <hip/hip_runtime.h>
#include <math.h>

#define LN_EPS 1e-5f

constexpr int D = 1024;
constexpr int S = 4096;
constexpr int B = 4;
constexpr int KH = 512;                 // Hermitian-packed spectral columns
constexpr float NEG_TWO_PI = -6.283185307179586f;

__device__ __forceinline__ float2 cmul(float2 a, float2 b) {
    return make_float2(a.x * b.x - a.y * b.y, a.x * b.y + a.y * b.x);
}
__device__ __forceinline__ float2 csq(float2 a) {
    return make_float2(a.x * a.x - a.y * a.y, 2.f * a.x * a.y);
}

// Bank swizzle for the 1024-float re/im arrays (radix-4 stage patterns -> <=2-way).
__device__ __forceinline__ int SWX(int a) {
    int r = a;
    r ^= (-((a >> 5) & 1)) & 5;
    r ^= (-((a >> 6) & 1)) & 10;
    r ^= (-((a >> 7) & 1)) & 17;
    return r;
}

// ---------------------------------------------------------------------------
// Kernel A: two rows per block. LayerNorm both rows, pack c = xn0 + i*xn1,
// one 1024-pt radix-4 FFT, untangle, store Hermitian-half spectra (512 cols;
// col 0 packs the two real columns k=0 and k=512 as Y[.,0] + i*Y[.,512]).
// ---------------------------------------------------------------------------
__global__ __launch_bounds__(256) void ln_fft_d(const float* __restrict__ x,
                                                const float* __restrict__ gamma,
                                                const float* __restrict__ beta,
                                                float2* __restrict__ y) {
    __shared__ float re[D];
    __shared__ float im[D];
    __shared__ float2 twA[256];   // W_1024^t
    __shared__ float red[36];

    const int tid = threadIdx.x;
    const size_t row0 = (size_t)blockIdx.x * 2;

    {   // twiddle table
        float sn, c;
        __sincosf(NEG_TWO_PI * (float)tid * (1.0f / 1024.0f), &sn, &c);
        twA[tid] = make_float2(c, sn);
    }

    // ---- load both rows (float4), LN statistics for each ----
    const float4 a4 = ((const float4*)(x + row0 * D))[tid];
    const float4 c4 = ((const float4*)(x + (row0 + 1) * D))[tid];
    float s0 = a4.x + a4.y + a4.z + a4.w;
    float q0 = a4.x * a4.x + a4.y * a4.y + a4.z * a4.z + a4.w * a4.w;
    float s1 = c4.x + c4.y + c4.z + c4.w;
    float q1 = c4.x * c4.x + c4.y * c4.y + c4.z * c4.z + c4.w * c4.w;
#pragma unroll
    for (int off = 32; off; off >>= 1) {
        s0 += __shfl_down(s0, off); q0 += __shfl_down(q0, off);
        s1 += __shfl_down(s1, off); q1 += __shfl_down(q1, off);
    }
    const int wid = tid >> 6;
    if ((tid & 63) == 0) { red[wid] = s0; red[8 + wid] = q0; red[16 + wid] = s1; red[24 + wid] = q1; }
    __syncthreads();
    if (tid == 0) {
        float S0 = red[0] + red[1] + red[2] + red[3];
        float Q0 = red[8] + red[9] + red[10] + red[11];
        float S1 = red[16] + red[17] + red[18] + red[19];
        float Q1 = red[24] + red[25] + red[26] + red[27];
        float m0 = S0 * (1.0f / D), m1 = S1 * (1.0f / D);
        red[32] = m0; red[33] = rsqrtf(Q0 * (1.0f / D) - m0 * m0 + LN_EPS);
        red[34] = m1; red[35] = rsqrtf(Q1 * (1.0f / D) - m1 * m1 + LN_EPS);
    }
    __syncthreads();
    const float m0 = red[32], r0 = red[33], m1 = red[34], r1 = red[35];

    // ---- normalize both rows, pack as complex, scatter digit-reversed ----
    const float4 g4 = ((const float4*)gamma)[tid];
    const float4 b4 = ((const float4*)beta)[tid];
    const float av[4] = {a4.x, a4.y, a4.z, a4.w};
    const float cv[4] = {c4.x, c4.y, c4.z, c4.w};
    const float gg[4] = {g4.x, g4.y, g4.z, g4.w};
    const float bb[4] = {b4.x, b4.y, b4.z, b4.w};
#pragma unroll
    for (int j = 0; j < 4; ++j) {
        int i = 4 * tid + j;
        unsigned br = __brev((unsigned)i) >> 22;                     // 10-bit reverse
        int dr = (int)(((br & 0x155u) << 1) | ((br & 0x2AAu) >> 1)); // pair-swap
        int p = SWX(dr);
        re[p] = (av[j] - m0) * r0 * gg[j] + bb[j];
        im[p] = (cv[j] - m1) * r1 * gg[j] + bb[j];
    }
    __syncthreads();

    // ---- 5 radix-4 DIT stages ----
#pragma unroll
    for (int st = 0; st < 5; ++st) {
        const int lq = 2 * st;
        const int q = 1 << lq;
        const int j = tid & (q - 1);
        const int i0 = ((tid & ~(q - 1)) << 2) + j;
        const int p0 = SWX(i0);
        const int p1 = SWX(i0 + q);
        const int p2 = SWX(i0 + 2 * q);
        const int p3 = SWX(i0 + 3 * q);
        const float2 w1 = twA[j << (8 - lq)];
        const float2 w2 = csq(w1);
        const float2 w3 = cmul(w1, w2);
        float2 a0 = make_float2(re[p0], im[p0]);
        float2 a1 = cmul(make_float2(re[p1], im[p1]), w1);
        float2 a2 = cmul(make_float2(re[p2], im[p2]), w2);
        float2 a3 = cmul(make_float2(re[p3], im[p3]), w3);
        float t0r = a0.x + a2.x, t0i = a0.y + a2.y;
        float t1r = a0.x - a2.x, t1i = a0.y - a2.y;
        float t2r = a1.x + a3.x, t2i = a1.y + a3.y;
        float t3r = a1.y - a3.y, t3i = a3.x - a1.x;   // -i*(a1-a3)
        re[p0] = t0r + t2r; im[p0] = t0i + t2i;
        re[p1] = t1r + t3r; im[p1] = t1i + t3i;
        re[p2] = t0r - t2r; im[p2] = t0i - t2i;
        re[p3] = t1r - t3r; im[p3] = t1i - t3i;
        __syncthreads();
    }

    // ---- untangle C into the two real-row spectra, Hermitian-packed store ----
    float2* y0 = y + row0 * KH;
    float2* y1 = y0 + KH;
    if (tid == 0) {
        int pa = SWX(0), pb = SWX(512);
        y0[0] = make_float2(re[pa], re[pb]);   // (Y0[0], Y0[512]) both real
        y1[0] = make_float2(im[pa], im[pb]);   // (Y1[0], Y1[512]) both real
    } else {
        int kc = tid;
        int p = SWX(kc), pq = SWX(1024 - kc);
        float2 cA = make_float2(re[p], im[p]);
        float2 cB = make_float2(re[pq], im[pq]);
        y0[kc] = make_float2(0.5f * (cA.x + cB.x), 0.5f * (cA.y - cB.y));
        y1[kc] = make_float2(0.5f * (cA.y + cB.y), 0.5f * (cB.x - cA.x));
    }
    {
        int kc = tid + 256;
        int p = SWX(kc), pq = SWX(1024 - kc);
        float2 cA = make_float2(re[p], im[p]);
        float2 cB = make_float2(re[pq], im[pq]);
        y0[kc] = make_float2(0.5f * (cA.x + cB.x), 0.5f * (cA.y - cB.y));
        y1[kc] = make_float2(0.5f * (cA.y + cB.y), 0.5f * (cB.x - cA.x));
    }
}

// ---------------------------------------------------------------------------
// Four-step FFT over S = 4096 = 64 x 64 on the 512 packed columns.
// Pass 1 (in place): fixed n1: FFT64 over n2, twiddle W_4096^{n1*k2},
//                    store Z[b][k2][n1][kc].
// ---------------------------------------------------------------------------
__global__ __launch_bounds__(256) void fft_s_p1(const float2* y, float2* z) {
    __shared__ float2 tile[64 * 64];     // [row][col], lane=col: conflict-free
    __shared__ float2 tw64[16];

    const int bid = blockIdx.x;
    const int dt = bid & 7;
    const int n1 = (bid >> 3) & 63;
    const int b  = bid >> 9;
    const int d0 = dt << 6;
    const int lane = threadIdx.x & 63;
    const int r4   = threadIdx.x >> 6;

    if (threadIdx.x < 16) {
        float sn, c;
        __sincosf(NEG_TWO_PI * (float)threadIdx.x * (1.0f / 64.0f), &sn, &c);
        tw64[threadIdx.x] = make_float2(c, sn);
    }

#pragma unroll
    for (int m = 0; m < 16; ++m) {
        int n2 = (m << 2) | r4;
        unsigned br = __brev((unsigned)n2) >> 26;
        int rr = (int)(((br & 0x15u) << 1) | ((br & 0x2Au) >> 1));
        tile[(rr << 6) | lane] =
            y[(size_t)((b << 12) | (n2 << 6) | n1) * KH + d0 + lane];
    }
    __syncthreads();

#pragma unroll
    for (int st = 0; st < 3; ++st) {
        const int lq = 2 * st;
        const int q = 1 << lq;
#pragma unroll
        for (int it = 0; it < 4; ++it) {
            int t = threadIdx.x + (it << 8);
            int d = t & 63;
            int bf = t >> 6;
            int j = bf & (q - 1);
            int i0 = ((bf & ~(q - 1)) << 2) + j;
            float2 w1 = tw64[j << (4 - lq)];
            float2 w2 = csq(w1);
            float2 w3 = cmul(w1, w2);
            float2 a0 = tile[(i0 << 6) | d];
            float2 a1 = cmul(tile[((i0 + q) << 6) | d], w1);
            float2 a2 = cmul(tile[((i0 + 2 * q) << 6) | d], w2);
            float2 a3 = cmul(tile[((i0 + 3 * q) << 6) | d], w3);
            float t0r = a0.x + a2.x, t0i = a0.y + a2.y;
            float t1r = a0.x - a2.x, t1i = a0.y - a2.y;
            float t2r = a1.x + a3.x, t2i = a1.y + a3.y;
            float t3r = a1.y - a3.y, t3i = a3.x - a1.x;
            tile[(i0 << 6) | d]           = make_float2(t0r + t2r, t0i + t2i);
            tile[((i0 + q) << 6) | d]     = make_float2(t1r + t3r, t1i + t3i);
            tile[((i0 + 2 * q) << 6) | d] = make_float2(t0r - t2r, t0i - t2i);
            tile[((i0 + 3 * q) << 6) | d] = make_float2(t1r - t3r, t1i - t3i);
        }
        __syncthreads();
    }

    const float ang0 = NEG_TWO_PI * (float)n1 * (1.0f / 4096.0f);
#pragma unroll
    for (int m = 0; m < 16; ++m) {
        int k2 = (m << 2) | r4;
        float2 vv = tile[(k2 << 6) | lane];
        float sn, c;
        __sincosf(ang0 * (float)k2, &sn, &c);
        z[(size_t)((b << 12) | (k2 << 6) | n1) * KH + d0 + lane] =
            make_float2(vv.x * c - vv.y * sn, vv.x * sn + vv.y * c);
    }
}

// ---------------------------------------------------------------------------
// Pass 2 + fused column-0 completion.
// Normal blocks (first B*64*8): fixed k2: FFT64 over n1 -> G_k[q], q=k2+64*k1;
//   write out[b][q][k] = Re G (k=1..511) and the Hermitian mirror
//   out[b][(S-q)%S][D-k] = Re G.  (k=0 lane skipped: packed column.)
// Tail blocks (B): complete the packed column 0 for one batch: FFT64 over n1
//   for ALL k2 (full 64x64 tile local), untangle H = G_0 + i*G_512, write
//   output columns 0 and 512.
// ---------------------------------------------------------------------------
__global__ __launch_bounds__(256) void fft_s_p2(const float2* __restrict__ z,
                                                float* __restrict__ out) {
    __shared__ float2 tile[64 * 64];
    __shared__ float2 tw64[16];

    const int lane = threadIdx.x & 63;
    const int r4   = threadIdx.x >> 6;

    if (threadIdx.x < 16) {
        float sn, c;
        __sincosf(NEG_TWO_PI * (float)threadIdx.x * (1.0f / 64.0f), &sn, &c);
        tw64[threadIdx.x] = make_float2(c, sn);
    }

    if (blockIdx.x < B * 64 * 8) {
        const int bid = blockIdx.x;
        const int dt = bid & 7;
        const int k2 = (bid >> 3) & 63;
        const int b  = bid >> 9;
        const int d0 = dt << 6;

#pragma unroll
        for (int m = 0; m < 16; ++m) {
            int n1 = (m << 2) | r4;
            unsigned br = __brev((unsigned)n1) >> 26;
            int rr = (int)(((br & 0x15u) << 1) | ((br & 0x2Au) >> 1));
            tile[(rr << 6) | lane] =
                z[(size_t)((b << 12) | (k2 << 6) | n1) * KH + d0 + lane];
        }
        __syncthreads();

#pragma unroll
        for (int st = 0; st < 3; ++st) {
            const int lq = 2 * st;
            const int q = 1 << lq;
#pragma unroll
            for (int it = 0; it < 4; ++it) {
                int t = threadIdx.x + (it << 8);
                int d = t & 63;
                int bf = t >> 6;
                int j = bf & (q - 1);
                int i0 = ((bf & ~(q - 1)) << 2) + j;
                float2 w1 = tw64[j << (4 - lq)];
                float2 w2 = csq(w1);
                float2 w3 = cmul(w1, w2);
                float2 a0 = tile[(i0 << 6) | d];
                float2 a1 = cmul(tile[((i0 + q) << 6) | d], w1);
                float2 a2 = cmul(tile[((i0 + 2 * q) << 6) | d], w2);
                float2 a3 = cmul(tile[((i0 + 3 * q) << 6) | d], w3);
                float t0r = a0.x + a2.x, t0i = a0.y + a2.y;
                float t1r = a0.x - a2.x, t1i = a0.y - a2.y;
                float t2r = a1.x + a3.x, t2i = a1.y + a3.y;
                float t3r = a1.y - a3.y, t3i = a3.x - a1.x;
                tile[(i0 << 6) | d]           = make_float2(t0r + t2r, t0i + t2i);
                tile[((i0 + q) << 6) | d]     = make_float2(t1r + t3r, t1i + t3i);
                tile[((i0 + 2 * q) << 6) | d] = make_float2(t0r - t2r, t0i - t2i);
                tile[((i0 + 3 * q) << 6) | d] = make_float2(t1r - t3r, t1i - t3i);
            }
            __syncthreads();
        }

        const int kc = d0 + lane;
#pragma unroll
        for (int m = 0; m < 16; ++m) {
            int k1 = (m << 2) | r4;
            int q = (k1 << 6) | k2;
            float v = tile[(k1 << 6) | lane].x;
            if (kc) {
                out[((size_t)(b << 12) + (size_t)q) * D + kc] = v;
                int qm = (S - q) & (S - 1);
                out[((size_t)(b << 12) + (size_t)qm) * D + (D - kc)] = v;
            }
        }
    } else {
        // ---- packed-column completion for batch b ----
        const int b = blockIdx.x - B * 64 * 8;

        // load Zcol[k2][n1] = z[b][k2][n1][0]; rows = n1 (digit-reversed), cols = k2
#pragma unroll
        for (int m = 0; m < 16; ++m) {
            int k2 = (m << 2) | r4;
            unsigned br = __brev((unsigned)lane) >> 26;   // lane = n1
            int rr = (int)(((br & 0x15u) << 1) | ((br & 0x2Au) >> 1));
            tile[(rr << 6) | k2] = z[(size_t)((b << 12) | (k2 << 6) | lane) * KH];
        }
        __syncthreads();

#pragma unroll
        for (int st = 0; st < 3; ++st) {
            const int lq = 2 * st;
            const int q = 1 << lq;
#pragma unroll
            for (int it = 0; it < 4; ++it) {
                int t = threadIdx.x + (it << 8);
                int d = t & 63;               // d = k2 (batch lane)
                int bf = t >> 6;
                int j = bf & (q - 1);
                int i0 = ((bf & ~(q - 1)) << 2) + j;
                float2 w1 = tw64[j << (4 - lq)];
                float2 w2 = csq(w1);
                float2 w3 = cmul(w1, w2);
                float2 a0 = tile[(i0 << 6) | d];
                float2 a1 = cmul(tile[((i0 + q) << 6) | d], w1);
                float2 a2 = cmul(tile[((i0 + 2 * q) << 6) | d], w2);
                float2 a3 = cmul(tile[((i0 + 3 * q) << 6) | d], w3);
                float t0r = a0.x + a2.x, t0i = a0.y + a2.y;
                float t1r = a0.x - a2.x, t1i = a0.y - a2.y;
                float t2r = a1.x + a3.x, t2i = a1.y + a3.y;
                float t3r = a1.y - a3.y, t3i = a3.x - a1.x;
                tile[(i0 << 6) | d]           = make_float2(t0r + t2r, t0i + t2i);
                tile[((i0 + q) << 6) | d]     = make_float2(t1r + t3r, t1i + t3i);
                tile[((i0 + 2 * q) << 6) | d] = make_float2(t0r - t2r, t0i - t2i);
                tile[((i0 + 3 * q) << 6) | d] = make_float2(t1r - t3r, t1i - t3i);
            }
            __syncthreads();
        }

        // tile[k1][k2] = H[q], q = k2 + 64*k1, H = G_0 + i*G_512.
        // Re G_0[q]   = (Re H[q] + Re H[qm]) / 2,  qm = (S-q) mod S
        // Re G_512[q] = (Im H[q] + Im H[qm]) / 2
#pragma unroll
        for (int m = 0; m < 16; ++m) {
            int k1 = (m << 2) | r4;
            int k2 = lane;
            int q = (k1 << 6) | k2;
            int k2m = (64 - k2) & 63;
            int k1m = (k2 == 0) ? ((64 - k1) & 63) : (63 - k1);
            float2 Hq = tile[(k1 << 6) | k2];
            float2 Hm = tile[(k1m << 6) | k2m];
            size_t ob = ((size_t)(b << 12) + (size_t)q) * D;
            out[ob]       = 0.5f * (Hq.x + Hm.x);
            out[ob + 512] = 0.5f * (Hq.y + Hm.y);
        }
    }
}

extern "C" void kernel_launch(void* const* d_in, const int* in_sizes, int n_in,
                              void* d_out, int out_size, void* d_ws, size_t ws_size,
                              hipStream_t stream) {
    const float* x     = (const float*)d_in[0];
    const float* gamma = (const float*)d_in[1];
    const float* beta  = (const float*)d_in[2];
    float* out = (float*)d_out;

    float2* y = (float2*)d_ws;   // 64 MB Hermitian-packed spectra; p1 in place

    ln_fft_d<<<B * S / 2, 256, 0, stream>>>(x, gamma, beta, y);
    fft_s_p1<<<B * 64 * 8, 256, 0, stream>>>(y, y);
    fft_s_p2<<<B * 64 * 8 + B, 256, 0, stream>>>(y, out);
}